// Round 2
// baseline (468.053 us; speedup 1.0000x reference)
//
#include <hip/hip_runtime.h>
#include <hip/hip_bf16.h>

// LSTM cell: B=4096, IN=1024, H=2048.
// R7: fused GEMM+epilogue. gate-interleaved weight pack (row 4h+g), 256x256 tile,
// 8 waves, BK=32, 4 LDS buffers, 2 barriers/K-tile (was 4), single 12-read burst
// with lgkmcnt(4) split, counted vmcnt(8), rectangular XCD mapping (4Mx16N per XCD),
// in-kernel LSTM epilogue via shfl_xor quad exchange + LDS repack -> fp32 out.

#define BATCH 4096
#define INW   1024
#define HID   2048
#define GK    3072   // HID + INW
#define GN    8192   // 4*HID

typedef __attribute__((ext_vector_type(8))) short short8;
typedef __attribute__((ext_vector_type(4))) float floatx4;

__device__ __forceinline__ unsigned short f2bf(float f) {
    union { float f; unsigned u; } v; v.f = f;
    unsigned r = v.u + 0x7FFFu + ((v.u >> 16) & 1u);
    return (unsigned short)(r >> 16);
}
__device__ __forceinline__ float sigf(float x) {
    return 1.0f / (1.0f + __expf(-x));
}
__device__ __forceinline__ float tanhfast(float x) {
    float t = __expf(fminf(fmaxf(2.0f * x, -30.0f), 30.0f));
    return (t - 1.0f) / (t + 1.0f);
}

// ---- pack kernel: fp32 -> bf16; W rows gate-interleaved: Wb row 4h+g = W_g[h] ----
__global__ __launch_bounds__(256) void pack_all(const float4* __restrict__ ph,
                                                const float4* __restrict__ x,
                                                const float4* __restrict__ Wi,
                                                const float4* __restrict__ Wf,
                                                const float4* __restrict__ Wo,
                                                const float4* __restrict__ Wc,
                                                unsigned short* __restrict__ hx,
                                                unsigned short* __restrict__ Wb) {
    long i = (long)blockIdx.x * 256 + threadIdx.x;
    const float4* src;
    unsigned short* dst;
    if (i < 1048576L) {            // prev_h [4096,2048] -> hx[:, 0:2048]
        int r  = (int)(i >> 8);
        int c8 = (int)(i & 255);
        src = ph + 2 * i;
        dst = hx + (size_t)r * GK + (size_t)c8 * 8;
    } else if (i < 1572864L) {     // x [4096,1024] -> hx[:, 2048:3072]
        long j = i - 1048576L;
        int r  = (int)(j >> 7);
        int c8 = (int)(j & 127);
        src = x + 2 * j;
        dst = hx + (size_t)r * GK + HID + (size_t)c8 * 8;
    } else {                        // W_g row h -> Wb row 4h+g (gate-interleaved)
        long j = i - 1572864L;
        const float4* Wg;
        int g;
        if (j < 786432L)            { Wg = Wi; g = 0; }
        else if (j < 1572864L)      { Wg = Wf; g = 1; j -= 786432L; }
        else if (j < 2359296L)      { Wg = Wo; g = 2; j -= 1572864L; }
        else                        { Wg = Wc; g = 3; j -= 2359296L; }
        src = Wg + 2 * j;
        int h  = (int)(j / 384);          // GK/8 = 384 chunks per row
        int kc = (int)(j - (long)h * 384);
        dst = Wb + (size_t)(4 * h + g) * GK + (size_t)kc * 8;
    }
    float4 v0 = src[0];
    float4 v1 = src[1];
    unsigned short o[8];
    o[0] = f2bf(v0.x); o[1] = f2bf(v0.y); o[2] = f2bf(v0.z); o[3] = f2bf(v0.w);
    o[4] = f2bf(v1.x); o[5] = f2bf(v1.y); o[6] = f2bf(v1.z); o[7] = f2bf(v1.w);
    *(short8*)dst = *(const short8*)o;
}

__device__ __forceinline__ void gld16(const unsigned short* g, unsigned short* l) {
    __builtin_amdgcn_global_load_lds((const __attribute__((address_space(1))) unsigned int*)g,
                                     (__attribute__((address_space(3))) unsigned int*)l,
                                     16, 0, 0);
}

template<int VM> __device__ __forceinline__ void wait_vm() {
    if constexpr (VM == 8)      asm volatile("s_waitcnt vmcnt(8)" ::: "memory");
    else if constexpr (VM == 4) asm volatile("s_waitcnt vmcnt(4)" ::: "memory");
    else if constexpr (VM == 0) asm volatile("s_waitcnt vmcnt(0)" ::: "memory");
    // VM == -1: no wait (final iteration)
}

// ---- fused GEMM + LSTM epilogue ----
// gates[M=4096, N=8192] = hx * Wb^T, col n <-> (h = n>>2, gate = n&3).
// 256x256 tile, 512 threads (8 waves, 2M x 4N), BK=32, 4 LDS tile-buffers.
// Per K-tile: issue 12 ds_read_b128 (8 then 4, sched_barrier-pinned) + 4
// global_load_lds, ONE barrier, lgkmcnt(4) -> MFMA m0-3, lgkmcnt(0) -> MFMA m4-7,
// vmcnt(8) (counted, never 0 in main loop), barrier.  2 barriers/K-tile.
// Buffer safety: stage of t+3 targets buf[(t-1)&3]; all reads of that buffer
// completed (lgkmcnt(0)) before barrier#2 of iter t-1, which precedes the stage.
__global__ __launch_bounds__(512, 2) void gemm_fused(const unsigned short* __restrict__ A,
                                                     const unsigned short* __restrict__ Bt,
                                                     const float* __restrict__ prev_c,
                                                     float* __restrict__ out) {
    __shared__ unsigned short lds[65536];   // 128 KiB: A bufs [0,32768), B bufs [32768,65536)
    const int tid  = threadIdx.x;
    const int wave = tid >> 6;
    const int lane = tid & 63;

    // rectangular XCD mapping: XCD x owns M in [4*(x&3), +4), N in [16*(x>>2), +16);
    // resident 32 blocks/XCD = 4M x 8N -> A missed by 2 XCDs, B by 4 (~240 MB L2 fill).
    const int bid = blockIdx.x;
    const int x = bid & 7, ii = bid >> 3;          // ii in 0..63
    const int mt = ((x & 3) << 2) + (ii & 3);      // 0..15
    const int nt = ((x >> 2) << 4) + (ii >> 2);    // 0..31
    const long row0 = (long)mt * 256;
    const long col0 = (long)nt * 256;

    const int wm = wave >> 2;   // 0..1 -> rows wm*128
    const int wn = wave & 3;    // 0..3 -> cols wn*64

    // staging source pointers (pre-swizzled chunk: slot t&3 holds global chunk c0)
    const int c0 = ((tid & 3) - ((tid >> 3) & 3)) & 3;
    const unsigned short* gA0 = A  + (row0 + (tid >> 2)) * GK + c0 * 8;
    const unsigned short* gB0 = Bt + (col0 + (tid >> 2)) * GK + c0 * 8;

#define STAGE_A(kt, b) do { \
        unsigned short* _d = &lds[(b) * 8192 + tid * 8]; \
        gld16(gA0 + (size_t)(kt) * 32, _d); \
        gld16(gA0 + 128 * GK + (size_t)(kt) * 32, _d + 4096); \
    } while (0)
#define STAGE_B(kt, b) do { \
        unsigned short* _d = &lds[32768 + (b) * 8192 + tid * 8]; \
        gld16(gB0 + (size_t)(kt) * 32, _d); \
        gld16(gB0 + 128 * GK + (size_t)(kt) * 32, _d + 4096); \
    } while (0)

    // fragment read offsets (ushort units); rotation swizzle slot = (cq + (fr>>1)) & 3
    const int fr = lane & 15;
    const int cq = lane >> 4;                       // k-chunk 0..3 (BK=32)
    const int slot = ((cq + (fr >> 1)) & 3) << 3;
    const int aoff = (wm * 128 + fr) * 32 + slot;   // + mi*512; rows +64 -> +2048
    const int boff = (wn * 64 + fr) * 32 + slot;    // + nj*512

    floatx4 acc[8][4];
    #pragma unroll
    for (int i = 0; i < 8; i++)
        #pragma unroll
        for (int j = 0; j < 4; j++)
            acc[i][j] = (floatx4)(0.0f);

    // prologue: stage tiles 0,1,2 (12 loads); vmcnt(8) drains tile 0
    STAGE_A(0, 0); STAGE_B(0, 0);
    STAGE_A(1, 1); STAGE_B(1, 1);
    STAGE_A(2, 2); STAGE_B(2, 2);
    asm volatile("s_waitcnt vmcnt(8)" ::: "memory");
    __builtin_amdgcn_s_barrier();

#define K_ITER(t, VMW, STG) do { \
        const unsigned short* bufA = &lds[((t) & 3) * 8192]; \
        const unsigned short* bufB = &lds[32768 + ((t) & 3) * 8192]; \
        short8 af[4], af2[4], bfv[4]; \
        _Pragma("unroll") \
        for (int i = 0; i < 4; i++) af[i]  = *(const short8*)&bufA[aoff + i * 512]; \
        _Pragma("unroll") \
        for (int j = 0; j < 4; j++) bfv[j] = *(const short8*)&bufB[boff + j * 512]; \
        __builtin_amdgcn_sched_barrier(0); /* pin: first 8 reads precede last 4 */ \
        _Pragma("unroll") \
        for (int i = 0; i < 4; i++) af2[i] = *(const short8*)&bufA[aoff + 2048 + i * 512]; \
        if (STG) { STAGE_A((t) + 3, ((t) + 3) & 3); STAGE_B((t) + 3, ((t) + 3) & 3); } \
        __builtin_amdgcn_s_barrier(); \
        asm volatile("s_waitcnt lgkmcnt(4)" ::: "memory"); \
        __builtin_amdgcn_sched_barrier(0); \
        __builtin_amdgcn_s_setprio(1); \
        _Pragma("unroll") \
        for (int i = 0; i < 4; i++) \
            _Pragma("unroll") \
            for (int j = 0; j < 4; j++) \
                acc[i][j] = __builtin_amdgcn_mfma_f32_16x16x32_bf16(af[i], bfv[j], acc[i][j], 0, 0, 0); \
        __builtin_amdgcn_s_setprio(0); \
        asm volatile("s_waitcnt lgkmcnt(0)" ::: "memory"); \
        __builtin_amdgcn_sched_barrier(0); \
        __builtin_amdgcn_s_setprio(1); \
        _Pragma("unroll") \
        for (int i = 0; i < 4; i++) \
            _Pragma("unroll") \
            for (int j = 0; j < 4; j++) \
                acc[4 + i][j] = __builtin_amdgcn_mfma_f32_16x16x32_bf16(af2[i], bfv[j], acc[4 + i][j], 0, 0, 0); \
        __builtin_amdgcn_s_setprio(0); \
        wait_vm<VMW>(); \
        __builtin_amdgcn_s_barrier(); \
    } while (0)

    // main loop: 96 K-tiles of 32. t < 93 stages tile t+3 (last staged = 95).
    int t = 0;
    for (; t < 93; ++t) K_ITER(t, 8, true);
    K_ITER(93, 4, false);   // drain tile 94 (tile 95 stays in flight)
    K_ITER(94, 0, false);   // drain tile 95
    K_ITER(95, -1, false);

#undef K_ITER
#undef STAGE_A
#undef STAGE_B

    // ---- fused LSTM epilogue ----
    // C/D layout: col = lane&15, row = (lane>>4)*4 + reg  [m89-verified]
    // col_loc = wn*64 + nj*16 + cc -> gate = cc&3, h_loc = wn*16 + nj*4 + (cc>>2).
    // Lanes {4k..4k+3} of a quad hold gates i,f,o,c of the SAME (row, h):
    // exchange via 3x shfl_xor, combine, stage through LDS, coalesced fp32 out.
    const int cr = (lane >> 4) << 2;
    const int cc = lane & 15;
    const int g  = lane & 3;
    float* nhl = (float*)lds;            // [256][64] fp32 = 64 KB
    float* ncl = nhl + 16384;            // [256][64] fp32 = 64 KB
    const long hbase = col0 >> 2;        // global h base of this block

    #pragma unroll
    for (int mi = 0; mi < 8; mi++) {
        #pragma unroll
        for (int nj = 0; nj < 4; nj++) {
            #pragma unroll
            for (int r = 0; r < 4; r++) {
                const int row_loc = wm * 128 + mi * 16 + cr + r;
                const int h_loc   = wn * 16 + nj * 4 + (cc >> 2);
                float v   = acc[mi][nj][r];
                float act = (g == 3) ? tanhfast(v) : sigf(v);
                float t1 = __shfl_xor(act, 1);
                float t2 = __shfl_xor(act, 2);
                float t3 = __shfl_xor(act, 3);
                // gate m lives in t_{m^g} (t0 = act)
                float iv = (g == 0) ? act : (g == 1) ? t1 : (g == 2) ? t2 : t3;
                float fv = (g == 0) ? t1 : (g == 1) ? act : (g == 2) ? t3 : t2;
                float ov = (g == 0) ? t2 : (g == 1) ? t3 : (g == 2) ? act : t1;
                float cv = (g == 0) ? t3 : (g == 1) ? t2 : (g == 2) ? t1 : act;
                float pc = prev_c[(row0 + row_loc) * (long)HID + hbase + h_loc];
                float nc = fv * pc + iv * cv;
                float nh = ov * tanhfast(nc);
                if (g == 0)      nhl[row_loc * 64 + h_loc] = nh;
                else if (g == 1) ncl[row_loc * 64 + h_loc] = nc;
            }
        }
    }
    __syncthreads();

    // coalesced fp32 writeback: out = [next_h (4096x2048) | next_c (4096x2048)]
    #pragma unroll
    for (int p = 0; p < 8; p++) {
        const int idx = p * 512 + tid;          // 0..4095
        const int row_loc = idx >> 4;
        const int h4 = (idx & 15) << 2;
        float4 vh = *(float4*)&nhl[row_loc * 64 + h4];
        float4 vc = *(float4*)&ncl[row_loc * 64 + h4];
        *(float4*)&out[(row0 + row_loc) * (long)HID + hbase + h4] = vh;
        *(float4*)&out[(size_t)BATCH * HID + (row0 + row_loc) * (long)HID + hbase + h4] = vc;
    }
}

extern "C" void kernel_launch(void* const* d_in, const int* in_sizes, int n_in,
                              void* d_out, int out_size, void* d_ws, size_t ws_size,
                              hipStream_t stream) {
    const float* x   = (const float*)d_in[0];
    const float* ph  = (const float*)d_in[1];
    const float* pc  = (const float*)d_in[2];
    const float* Wi  = (const float*)d_in[3];
    const float* Wf  = (const float*)d_in[4];
    const float* Wo  = (const float*)d_in[5];
    const float* Wc  = (const float*)d_in[6];

    // workspace (bf16): hx [4096,3072] | Wb [8192,3072]  (~75 MB; gates eliminated)
    unsigned short* hx = (unsigned short*)d_ws;
    unsigned short* Wb = hx + (size_t)BATCH * GK;
    float* out = (float*)d_out;

    pack_all<<<18432, 256, 0, stream>>>((const float4*)ph, (const float4*)x,
                                        (const float4*)Wi, (const float4*)Wf,
                                        (const float4*)Wo, (const float4*)Wc,
                                        hx, Wb);

    gemm_fused<<<512, 512, 0, stream>>>(hx, Wb, pc, out);
}

// Round 3
// 402.167 us; speedup vs baseline: 1.1638x; 1.1638x over previous
//
#include <hip/hip_runtime.h>
#include <hip/hip_bf16.h>

// LSTM cell: B=4096, IN=1024, H=2048.
// R8: fused GEMM+epilogue v2. Gate-interleaved weight pack (row 4h+g).
// 256x256 tile, 8 waves, BK=32, 4 LDS buffers, ONE barrier per K-tile
// (MFMA m4-7 overlaps next tile's read burst), counted vmcnt(8),
// rectangular XCD mapping (kept from R7: FETCH 405->165 MB).
// Epilogue: stage raw fp32 gates to LDS [128][256] in two row-half passes;
// combine reads (i,f,o,c) as ONE float4, prev_c coalesced, all lanes active,
// no shuffles; nh/nc written straight to global.

#define BATCH 4096
#define INW   1024
#define HID   2048
#define GK    3072   // HID + INW
#define GN    8192   // 4*HID

typedef __attribute__((ext_vector_type(8))) short short8;
typedef __attribute__((ext_vector_type(4))) float floatx4;

__device__ __forceinline__ unsigned short f2bf(float f) {
    union { float f; unsigned u; } v; v.f = f;
    unsigned r = v.u + 0x7FFFu + ((v.u >> 16) & 1u);
    return (unsigned short)(r >> 16);
}
__device__ __forceinline__ float sigf(float x) {
    return 1.0f / (1.0f + __expf(-x));
}
__device__ __forceinline__ float tanhfast(float x) {
    float t = __expf(fminf(fmaxf(2.0f * x, -30.0f), 30.0f));
    return (t - 1.0f) / (t + 1.0f);
}

// ---- pack kernel: fp32 -> bf16; W rows gate-interleaved: Wb row 4h+g = W_g[h] ----
__global__ __launch_bounds__(256) void pack_all(const float4* __restrict__ ph,
                                                const float4* __restrict__ x,
                                                const float4* __restrict__ Wi,
                                                const float4* __restrict__ Wf,
                                                const float4* __restrict__ Wo,
                                                const float4* __restrict__ Wc,
                                                unsigned short* __restrict__ hx,
                                                unsigned short* __restrict__ Wb) {
    long i = (long)blockIdx.x * 256 + threadIdx.x;
    const float4* src;
    unsigned short* dst;
    if (i < 1048576L) {            // prev_h [4096,2048] -> hx[:, 0:2048]
        int r  = (int)(i >> 8);
        int c8 = (int)(i & 255);
        src = ph + 2 * i;
        dst = hx + (size_t)r * GK + (size_t)c8 * 8;
    } else if (i < 1572864L) {     // x [4096,1024] -> hx[:, 2048:3072]
        long j = i - 1048576L;
        int r  = (int)(j >> 7);
        int c8 = (int)(j & 127);
        src = x + 2 * j;
        dst = hx + (size_t)r * GK + HID + (size_t)c8 * 8;
    } else {                        // W_g row h -> Wb row 4h+g (gate-interleaved)
        long j = i - 1572864L;
        const float4* Wg;
        int g;
        if (j < 786432L)            { Wg = Wi; g = 0; }
        else if (j < 1572864L)      { Wg = Wf; g = 1; j -= 786432L; }
        else if (j < 2359296L)      { Wg = Wo; g = 2; j -= 1572864L; }
        else                        { Wg = Wc; g = 3; j -= 2359296L; }
        src = Wg + 2 * j;
        int h  = (int)(j / 384);          // GK/8 = 384 chunks per row
        int kc = (int)(j - (long)h * 384);
        dst = Wb + (size_t)(4 * h + g) * GK + (size_t)kc * 8;
    }
    float4 v0 = src[0];
    float4 v1 = src[1];
    unsigned short o[8];
    o[0] = f2bf(v0.x); o[1] = f2bf(v0.y); o[2] = f2bf(v0.z); o[3] = f2bf(v0.w);
    o[4] = f2bf(v1.x); o[5] = f2bf(v1.y); o[6] = f2bf(v1.z); o[7] = f2bf(v1.w);
    *(short8*)dst = *(const short8*)o;
}

__device__ __forceinline__ void gld16(const unsigned short* g, unsigned short* l) {
    __builtin_amdgcn_global_load_lds((const __attribute__((address_space(1))) unsigned int*)g,
                                     (__attribute__((address_space(3))) unsigned int*)l,
                                     16, 0, 0);
}

template<int VM> __device__ __forceinline__ void wait_vm() {
    if constexpr (VM == 8)      asm volatile("s_waitcnt vmcnt(8)" ::: "memory");
    else if constexpr (VM == 4) asm volatile("s_waitcnt vmcnt(4)" ::: "memory");
    else if constexpr (VM == 0) asm volatile("s_waitcnt vmcnt(0)" ::: "memory");
    // VM == -1: no wait (final iteration)
}

// ---- fused GEMM + LSTM epilogue ----
// gates[M=4096, N=8192] = hx * Wb^T, col n <-> (h = n>>2, gate = n&3).
// Per K-tile: 12 ds_read_b128 + 4 global_load_lds issued up front;
// lgkmcnt(4) -> MFMA m0-3; lgkmcnt(0) + vmcnt(8) -> s_barrier -> MFMA m4-7.
// ONE barrier/K-tile; MFMA m4-7 overlaps the NEXT tile's read+stage burst
// across waves.  Hazards:
//  - reads of buf[t] all complete (lgkmcnt(0)) before barrier of iter t;
//    gld into buf[t] reissued at iter t+1 AFTER that barrier -> no WAR race.
//  - wave Y's gld of tile t+1 drained by Y's vmcnt(8) before barrier of
//    iter t; wave X reads buf[t+1] after that barrier -> no RAW race.
__global__ __launch_bounds__(512, 2) void gemm_fused(const unsigned short* __restrict__ A,
                                                     const unsigned short* __restrict__ Bt,
                                                     const float* __restrict__ prev_c,
                                                     float* __restrict__ out) {
    __shared__ unsigned short lds[65536];   // 128 KiB: A bufs [0,32768), B bufs [32768,65536)
    const int tid  = threadIdx.x;
    const int wave = tid >> 6;
    const int lane = tid & 63;

    // rectangular XCD mapping: XCD x owns M-tiles [4*(x&3),+4) x N-tiles [16*(x>>2),+16)
    const int bid = blockIdx.x;
    const int x = bid & 7, ii = bid >> 3;          // ii in 0..63
    const int mt = ((x & 3) << 2) + (ii & 3);      // 0..15
    const int nt = ((x >> 2) << 4) + (ii >> 2);    // 0..31
    const long row0 = (long)mt * 256;
    const long col0 = (long)nt * 256;

    const int wm = wave >> 2;   // 0..1 -> rows wm*128
    const int wn = wave & 3;    // 0..3 -> cols wn*64

    // staging source pointers (pre-swizzled chunk: slot t&3 holds global chunk c0)
    const int c0 = ((tid & 3) - ((tid >> 3) & 3)) & 3;
    const unsigned short* gA0 = A  + (row0 + (tid >> 2)) * GK + c0 * 8;
    const unsigned short* gB0 = Bt + (col0 + (tid >> 2)) * GK + c0 * 8;

#define STAGE_A(kt, b) do { \
        unsigned short* _d = &lds[(b) * 8192 + tid * 8]; \
        gld16(gA0 + (size_t)(kt) * 32, _d); \
        gld16(gA0 + 128 * GK + (size_t)(kt) * 32, _d + 4096); \
    } while (0)
#define STAGE_B(kt, b) do { \
        unsigned short* _d = &lds[32768 + (b) * 8192 + tid * 8]; \
        gld16(gB0 + (size_t)(kt) * 32, _d); \
        gld16(gB0 + 128 * GK + (size_t)(kt) * 32, _d + 4096); \
    } while (0)

    // fragment read offsets (ushort units); rotation swizzle slot = (cq + (fr>>1)) & 3
    const int fr = lane & 15;
    const int cq = lane >> 4;                       // k-chunk 0..3 (BK=32)
    const int slot = ((cq + (fr >> 1)) & 3) << 3;
    const int aoff = (wm * 128 + fr) * 32 + slot;   // + mi*512; rows +64 -> +2048
    const int boff = (wn * 64 + fr) * 32 + slot;    // + nj*512

    floatx4 acc[8][4];
    #pragma unroll
    for (int i = 0; i < 8; i++)
        #pragma unroll
        for (int j = 0; j < 4; j++)
            acc[i][j] = (floatx4)(0.0f);

    // prologue: stage tiles 0,1,2 (12 loads); vmcnt(8) drains tile 0
    STAGE_A(0, 0); STAGE_B(0, 0);
    STAGE_A(1, 1); STAGE_B(1, 1);
    STAGE_A(2, 2); STAGE_B(2, 2);
    asm volatile("s_waitcnt vmcnt(8)" ::: "memory");
    __builtin_amdgcn_s_barrier();

#define K_ITER(t, VMW, STG) do { \
        const unsigned short* bufA = &lds[((t) & 3) * 8192]; \
        const unsigned short* bufB = &lds[32768 + ((t) & 3) * 8192]; \
        short8 af[4], af2[4], bfv[4]; \
        _Pragma("unroll") \
        for (int i = 0; i < 4; i++) af[i]  = *(const short8*)&bufA[aoff + i * 512]; \
        _Pragma("unroll") \
        for (int j = 0; j < 4; j++) bfv[j] = *(const short8*)&bufB[boff + j * 512]; \
        __builtin_amdgcn_sched_barrier(0); /* pin: first 8 reads precede last 4 */ \
        _Pragma("unroll") \
        for (int i = 0; i < 4; i++) af2[i] = *(const short8*)&bufA[aoff + 2048 + i * 512]; \
        if (STG) { STAGE_A((t) + 3, ((t) + 3) & 3); STAGE_B((t) + 3, ((t) + 3) & 3); } \
        asm volatile("s_waitcnt lgkmcnt(4)" ::: "memory"); \
        __builtin_amdgcn_sched_barrier(0); \
        __builtin_amdgcn_s_setprio(1); \
        _Pragma("unroll") \
        for (int i = 0; i < 4; i++) \
            _Pragma("unroll") \
            for (int j = 0; j < 4; j++) \
                acc[i][j] = __builtin_amdgcn_mfma_f32_16x16x32_bf16(af[i], bfv[j], acc[i][j], 0, 0, 0); \
        __builtin_amdgcn_s_setprio(0); \
        asm volatile("s_waitcnt lgkmcnt(0)" ::: "memory"); \
        __builtin_amdgcn_sched_barrier(0); \
        wait_vm<VMW>(); \
        __builtin_amdgcn_s_barrier(); \
        __builtin_amdgcn_sched_barrier(0); \
        __builtin_amdgcn_s_setprio(1); \
        _Pragma("unroll") \
        for (int i = 0; i < 4; i++) \
            _Pragma("unroll") \
            for (int j = 0; j < 4; j++) \
                acc[4 + i][j] = __builtin_amdgcn_mfma_f32_16x16x32_bf16(af2[i], bfv[j], acc[4 + i][j], 0, 0, 0); \
        __builtin_amdgcn_s_setprio(0); \
    } while (0)

    // main loop: 96 K-tiles of 32. t < 93 stages tile t+3 (last staged = 95).
    int t = 0;
    for (; t < 93; ++t) K_ITER(t, 8, true);
    K_ITER(93, 4, false);   // drain tile 94 (tile 95 stays in flight)
    K_ITER(94, 0, false);   // drain tile 95
    K_ITER(95, -1, false);

#undef K_ITER
#undef STAGE_A
#undef STAGE_B

    // ---- fused LSTM epilogue v2 ----
    // C/D layout: col = lane&15, row = (lane>>4)*4 + reg  [m89-verified]
    // acc[mi] covers local rows mi*16 + cr + r within the wave's wm half.
    // Two passes over row halves; gates staged raw fp32 into LDS [128][256]
    // (exactly 128 KiB). Columns are gate-interleaved: col = 4*h_loc + g,
    // so the combine reads (i,f,o,c) as one contiguous float4.
    const int cr = (lane >> 4) << 2;
    const int cc = lane & 15;
    const long hbase = col0 >> 2;        // global h base of this block (64 h per block)
    float* gbuf = (float*)lds;           // [128][256] fp32

    #pragma unroll 1
    for (int pass = 0; pass < 2; ++pass) {
        __syncthreads();
        if (wm == pass) {
            #pragma unroll
            for (int mi = 0; mi < 8; mi++) {
                #pragma unroll
                for (int nj = 0; nj < 4; nj++) {
                    const int colb = wn * 64 + nj * 16 + cc;
                    #pragma unroll
                    for (int r = 0; r < 4; r++)
                        gbuf[(mi * 16 + cr + r) * 256 + colb] = acc[mi][nj][r];
                }
            }
        }
        __syncthreads();
        #pragma unroll 4
        for (int p = 0; p < 16; p++) {
            const int u   = p * 512 + tid;   // 0..8191
            const int row = u >> 6;          // 0..127 within this half
            const int h   = u & 63;
            float4 g4 = *(const float4*)&gbuf[row * 256 + h * 4];  // (i,f,o,c)
            const long grow = row0 + pass * 128 + row;
            const long ob   = grow * (long)HID + hbase + h;
            float pc = prev_c[ob];
            float iv = sigf(g4.x);
            float fv = sigf(g4.y);
            float ov = sigf(g4.z);
            float cv = tanhfast(g4.w);
            float nc = fv * pc + iv * cv;
            float nh = ov * tanhfast(nc);
            out[ob] = nh;
            out[(size_t)BATCH * HID + ob] = nc;
        }
    }
}

extern "C" void kernel_launch(void* const* d_in, const int* in_sizes, int n_in,
                              void* d_out, int out_size, void* d_ws, size_t ws_size,
                              hipStream_t stream) {
    const float* x   = (const float*)d_in[0];
    const float* ph  = (const float*)d_in[1];
    const float* pc  = (const float*)d_in[2];
    const float* Wi  = (const float*)d_in[3];
    const float* Wf  = (const float*)d_in[4];
    const float* Wo  = (const float*)d_in[5];
    const float* Wc  = (const float*)d_in[6];

    // workspace (bf16): hx [4096,3072] | Wb [8192,3072]  (~75 MB; gates never hit HBM)
    unsigned short* hx = (unsigned short*)d_ws;
    unsigned short* Wb = hx + (size_t)BATCH * GK;
    float* out = (float*)d_out;

    pack_all<<<18432, 256, 0, stream>>>((const float4*)ph, (const float4*)x,
                                        (const float4*)Wi, (const float4*)Wf,
                                        (const float4*)Wo, (const float4*)Wc,
                                        hx, Wb);

    gemm_fused<<<512, 512, 0, stream>>>(hx, Wb, pc, out);
}